// Round 3
// baseline (135.301 us; speedup 1.0000x reference)
//
#include <hip/hip_runtime.h>
#include <stdint.h>

// TypedLinear: out[i] = W[types[i]] @ x[i] + b[types[i]]
// N=65536, IN=OUT=256, T=8, fp32 in/out. bf16-MFMA grouped-GEMM via type bucketing.
// This rev: BM=32 x BN=256 tiles -> 2048+ blocks, 5 blocks/CU (20 waves/CU) for
// latency hiding via TLP + natural phase decorrelation. W pre-packed (coalesced
// pack kernel) into MFMA-fragment order, read from L2. Nontemporal out stores.

#define NROWS 65536
#define NTYPES 8
#define KDIM 256
#define ODIM 256
#define BM 32
#define MAX_TILES (NROWS / BM + NTYPES)   // 2056 worst case

typedef __attribute__((ext_vector_type(8))) short short8;
typedef __attribute__((ext_vector_type(4))) float f32x4;

__device__ __forceinline__ unsigned short f2bf(float f) {
    // round-to-nearest-even fp32 -> bf16
    unsigned int u = __float_as_uint(f);
    u += 0x7fffu + ((u >> 16) & 1u);
    return (unsigned short)(u >> 16);
}

// ---------------- fused prep + bucket ----------------
// blocks [0,256): pack W fp32 -> bf16 in MFMA-fragment order, fully coalesced:
//   thread gid: R = gid>>5 (global W row, t*256 + r), c32 = gid&31 (8-float chunk)
//   reads 32B contiguous, writes one 16B fragment record:
//   Wp[((t*16+f)*8+q)*512 + l*8 + e] = bf16(W[t][f*16+(l&15)][q*32+(l>>4)*8+e])
// blocks [256,512): per-type index lists via LDS histogram -> 8 global atomics.
// cnt pre-zeroed by hipMemsetAsync.
__global__ void prep_bucket_kernel(const float* __restrict__ W,
                                   unsigned short* __restrict__ Wp,
                                   const int* __restrict__ types,
                                   int* __restrict__ cnt,
                                   int* __restrict__ idx) {
    const int b = blockIdx.x;
    if (b < 256) {
        const int gid = b * 256 + threadIdx.x;      // 0..65535
        const int R   = gid >> 5;                   // W row: t*256 + r
        const int c32 = gid & 31;                   // which 8-float chunk of the row
        const int t  = R >> 8;
        const int r  = R & 255;
        const int f  = r >> 4;
        const int rr = r & 15;
        const int q  = c32 >> 2;
        const int l  = (c32 & 3) * 16 + rr;
        const float* src = W + (size_t)R * KDIM + c32 * 8;
        const float4 v0 = *(const float4*)src;
        const float4 v1 = *(const float4*)(src + 4);
        ushort4 p0, p1;
        p0.x = f2bf(v0.x); p0.y = f2bf(v0.y); p0.z = f2bf(v0.z); p0.w = f2bf(v0.w);
        p1.x = f2bf(v1.x); p1.y = f2bf(v1.y); p1.z = f2bf(v1.z); p1.w = f2bf(v1.w);
        ushort4* dst = (ushort4*)(Wp + (size_t)(((t * 16 + f) * 8 + q) * 512 + l * 8));
        dst[0] = p0; dst[1] = p1;
    } else {
        __shared__ int h[NTYPES];
        __shared__ int base[NTYPES];
        int i = (b - 256) * 256 + threadIdx.x;
        if (threadIdx.x < NTYPES) h[threadIdx.x] = 0;
        __syncthreads();
        int t = types[i];
        int r = atomicAdd(&h[t], 1);
        __syncthreads();
        if (threadIdx.x < NTYPES)
            base[threadIdx.x] = atomicAdd(&cnt[threadIdx.x], h[threadIdx.x]);
        __syncthreads();
        idx[t * NROWS + base[t] + r] = i;
    }
}

// ---------------- grouped GEMM ----------------
// grid (MAX_TILES): flat m-tile -> (type, m0). 256 threads = 4 waves, each wave
// owns 64 output cols (wn = wave*64); all share the 32-row A tile.
// As: [32 rows][256 k] bf16 (16 KB), 16B-chunk XOR swizzle c' = c ^ (row&7).
// B frags: coalesced short8 loads from packed Wp (L2-resident, 1 MB total).
__global__ __launch_bounds__(256, 5)
void gemm_kernel(const float* __restrict__ x,
                 const float* __restrict__ bias,
                 const unsigned short* __restrict__ Wp,
                 const int* __restrict__ cnt,
                 const int* __restrict__ idx,
                 float* __restrict__ out) {
    // ---- flat tile id -> (type t, tile base m0); uniform scalar work
    const int bid = blockIdx.x;
    int t = -1, m0 = 0, count = 0, accum = 0;
    #pragma unroll
    for (int i = 0; i < NTYPES; ++i) {
        int c = cnt[i];
        int ntile = (c + BM - 1) / BM;
        if (t < 0 && bid < accum + ntile) { t = i; m0 = (bid - accum) * BM; count = c; }
        accum += ntile;
    }
    if (t < 0) return;                 // only a handful of tail blocks

    __shared__ unsigned short As[BM * KDIM];    // 16 KB, swizzled
    __shared__ int idx_s[BM];
    char* AsB = (char*)As;

    const int tid = threadIdx.x;
    const int srow = tid >> 3;       // 0..31: one LDS row per 8 lanes
    const int sc   = tid & 7;

    // ---- stage A: 32 rows x 256 fp32 -> bf16 LDS, one burst, one barrier.
    {
        const int gr = m0 + srow;
        const int xr = idx[t * NROWS + (gr < count ? gr : count - 1)];
        if (sc == 0) idx_s[srow] = xr;
        const float* xs = x + (size_t)xr * KDIM;
        float4 av[8];
        #pragma unroll
        for (int s = 0; s < 8; ++s)
            av[s] = *(const float4*)(xs + (s * 8 + sc) * 4);
        #pragma unroll
        for (int s = 0; s < 8; ++s) {
            const int slot = s * 8 + sc;             // float4 slot 0..63
            ushort4 pk;
            pk.x = f2bf(av[s].x); pk.y = f2bf(av[s].y);
            pk.z = f2bf(av[s].z); pk.w = f2bf(av[s].w);
            const int c = slot >> 1;                 // 16B chunk 0..31
            *(ushort4*)(AsB + srow * 512 + ((c ^ (srow & 7)) * 16) + (slot & 1) * 8) = pk;
        }
    }
    __syncthreads();

    const int wave = tid >> 6;       // 0..3, owns cols [wave*64, wave*64+64)
    const int lane = tid & 63;
    const int lr = lane & 15;
    const int lq = lane >> 4;

    const unsigned short* Wpt = Wp + (size_t)t * 16 * 8 * 512;   // type base

    f32x4 acc[2][4] = {};

    // ---- compute: 8 k32-chunks x 8 MFMAs; B frags streamed from L2.
    #pragma unroll
    for (int q = 0; q < 8; ++q) {
        short8 bf[4], af[2];
        #pragma unroll
        for (int j = 0; j < 4; ++j)
            bf[j] = *(const short8*)(Wpt + ((size_t)((wave * 4 + j) * 8 + q)) * 512
                                         + lane * 8);
        #pragma unroll
        for (int i = 0; i < 2; ++i) {
            const int row = i * 16 + lr;
            af[i] = *(const short8*)(AsB + row * 512
                                         + (((q << 2) + lq) ^ (row & 7)) * 16);
        }
        #pragma unroll
        for (int i = 0; i < 2; ++i)
            #pragma unroll
            for (int j = 0; j < 4; ++j)
                acc[i][j] = __builtin_amdgcn_mfma_f32_16x16x32_bf16(
                    af[i], bf[j], acc[i][j], 0, 0, 0);
    }

    // ---- epilogue: D col = lane&15, row = (lane>>4)*4 + reg. Nontemporal stores.
    float bv[4];
    #pragma unroll
    for (int j = 0; j < 4; ++j)
        bv[j] = bias[t * ODIM + wave * 64 + j * 16 + lr];

    #pragma unroll
    for (int i = 0; i < 2; ++i) {
        #pragma unroll
        for (int r = 0; r < 4; ++r) {
            const int lm = i * 16 + lq * 4 + r;
            const int gr = m0 + lm;
            if (gr < count) {
                const size_t orow = (size_t)idx_s[lm] * ODIM;
                #pragma unroll
                for (int j = 0; j < 4; ++j)
                    __builtin_nontemporal_store(
                        acc[i][j][r] + bv[j],
                        &out[orow + wave * 64 + j * 16 + lr]);
            }
        }
    }
}

extern "C" void kernel_launch(void* const* d_in, const int* in_sizes, int n_in,
                              void* d_out, int out_size, void* d_ws, size_t ws_size,
                              hipStream_t stream) {
    const float* x     = (const float*)d_in[0];
    const int*   types = (const int*)d_in[1];
    const float* W     = (const float*)d_in[2];
    const float* b     = (const float*)d_in[3];
    float* out = (float*)d_out;

    // ws layout: [0,32) cnt | [1024, 1024+2MB) idx | then 1MB packed bf16 W
    char* ws = (char*)d_ws;
    int* cnt = (int*)ws;
    int* idx = (int*)(ws + 1024);
    unsigned short* Wp = (unsigned short*)(ws + 1024 + (size_t)NTYPES * NROWS * sizeof(int));

    hipMemsetAsync(cnt, 0, NTYPES * sizeof(int), stream);
    prep_bucket_kernel<<<512, 256, 0, stream>>>(W, Wp, types, cnt, idx);
    gemm_kernel<<<MAX_TILES, 256, 0, stream>>>(x, b, Wp, cnt, idx, out);
}